// Round 10
// baseline (402.219 us; speedup 1.0000x reference)
//
#include <hip/hip_runtime.h>
#include <hip/hip_cooperative_groups.h>

namespace cg = cooperative_groups;

#define NN 100000
#define EE 1600000
#define NF 256
#define NH 128

#define BK 98        // buckets of 1024 nodes: ceil(100000/1024)
#define BNODE 1024
#define CHUNK 4096
#define NCHUNK ((EE + CHUNK - 1) / CHUNK)  // 391

typedef unsigned int u32;
typedef unsigned short u16;
typedef __attribute__((ext_vector_type(8))) short short8;
typedef __attribute__((ext_vector_type(4))) float f32x4;

static __device__ __forceinline__ u16 f2bf(float f) {
  u32 u = __float_as_uint(f);
  u32 r = (u + 0x7FFFu + ((u >> 16) & 1u)) >> 16;
  return (u16)r;
}
static __device__ __forceinline__ float bflo(u32 u) { return __uint_as_float(u << 16); }
static __device__ __forceinline__ float bfhi(u32 u) { return __uint_as_float(u & 0xFFFF0000u); }

// ================= k_edges: fused p0+bscan+p1+p2 (cooperative) =============
// 391 blocks x 256. Phase A: chunk hist + local sort (persists in LDS).
// Phase B (98 blocks): bucket totals/bases + per-bucket chunk-prefix -> gtab.
// Phase C: coalesced dump of sorted chunk into binned (no atomics).
// Phase D (98 blocks): per-bucket node hist/scan -> off/dinv; csr scatter
// confined to 64KB window (single-XCD L2 write-combines).
__global__ __launch_bounds__(256) void k_edges(const int* __restrict__ row,
                                               const int* __restrict__ col,
                                               u32* __restrict__ hist2d,
                                               u32* __restrict__ gtab,
                                               u32* __restrict__ bbaseG,
                                               u32* __restrict__ off,
                                               float* __restrict__ dinv,
                                               u32* __restrict__ binned,
                                               int* __restrict__ csr) {
  __shared__ u32 U[CHUNK];                 // A/C: keybuf | D: hist1024+cur
  __shared__ unsigned char bktbuf[CHUNK];
  __shared__ u32 hist[BK], lstart[BK], lofs[BK], gbl[BK], tot[BK];
  __shared__ u32 colv[512];
  __shared__ u32 bbs;
  cg::grid_group grid = cg::this_grid();
  int blk = blockIdx.x, t = threadIdx.x;

  // ---------- Phase A ----------
  int e0 = blk * CHUNK;
  int n = min(CHUNK, EE - e0);
  if (t < BK) hist[t] = 0;
  __syncthreads();
  for (int i = t; i < n; i += 256) {
    u32 d = (u32)col[e0 + i];
    atomicAdd(&hist[d >> 10], 1u);
  }
  __syncthreads();
  if (t == 0) {
    u32 s = 0;
    for (int b = 0; b < BK; b++) { lstart[b] = s; lofs[b] = s; s += hist[b]; }
  }
  __syncthreads();
  for (int i = t; i < n; i += 256) {
    u32 d = (u32)col[e0 + i];
    u32 s = (u32)row[e0 + i];
    u32 b = d >> 10;
    u32 p = atomicAdd(&lofs[b], 1u);
    U[p] = ((d & 1023u) << 17) | s;
    bktbuf[p] = (unsigned char)b;
  }
  __syncthreads();
  if (t < BK) hist2d[blk * BK + t] = hist[t];

  grid.sync();

  // ---------- Phase B (blocks 0..BK-1) ----------
  if (blk < BK) {
    int b = blk;
    if (t < BK) {
      u32 s = 0;
      for (int ch = 0; ch < NCHUNK; ch++) s += hist2d[ch * BK + t];
      tot[t] = s;
    }
    u32 o0 = (t < NCHUNK) ? hist2d[t * BK + b] : 0u;
    u32 o1 = (t + 256 < NCHUNK) ? hist2d[(t + 256) * BK + b] : 0u;
    colv[t] = o0;
    colv[t + 256] = o1;
    __syncthreads();
    if (t == 0) {
      u32 s = 0;
      for (int b2 = 0; b2 < b; b2++) s += tot[b2];
      bbs = s;
      bbaseG[b] = s;
      if (b == 0) { bbaseG[BK] = EE; off[NN] = EE; }
    }
    for (int d = 1; d < 512; d <<= 1) {
      u32 a0 = colv[t], a1 = colv[t + 256];
      u32 p0 = (t >= d) ? colv[t - d] : 0u;
      u32 p1 = (t + 256 >= d) ? colv[t + 256 - d] : 0u;
      __syncthreads();
      colv[t] = a0 + p0;
      colv[t + 256] = a1 + p1;
      __syncthreads();
    }
    u32 B0 = bbs;
    if (t < NCHUNK) gtab[t * BK + b] = B0 + colv[t] - o0;
    if (t + 256 < NCHUNK) gtab[(t + 256) * BK + b] = B0 + colv[t + 256] - o1;
  }

  grid.sync();

  // ---------- Phase C ----------
  if (t < BK) gbl[t] = gtab[blk * BK + t];
  __syncthreads();
  for (int i = t; i < n; i += 256) {
    u32 b = bktbuf[i];
    binned[gbl[b] + ((u32)i - lstart[b])] = U[i];
  }

  grid.sync();

  // ---------- Phase D (blocks 0..BK-1) ----------
  if (blk < BK) {
    int b = blk;
    u32 base = bbaseG[b];
    u32 cnt = bbaseG[b + 1] - base;
    u32* hist1024 = U;        // [0..1023]
    u32* cur = U + 1024;      // [1024..2047]
#pragma unroll
    for (int j = 0; j < 4; j++) hist1024[t + j * 256] = 0;
    __syncthreads();
    for (u32 i = t; i < cnt; i += 256)
      atomicAdd(&hist1024[binned[base + i] >> 17], 1u);
    __syncthreads();
    u32 c0 = hist1024[4 * t], c1 = hist1024[4 * t + 1];
    u32 c2 = hist1024[4 * t + 2], c3 = hist1024[4 * t + 3];
    u32 ts = c0 + c1 + c2 + c3;
    colv[t] = ts;
    __syncthreads();
    for (int d = 1; d < 256; d <<= 1) {
      u32 v = colv[t];
      u32 a = (t >= d) ? colv[t - d] : 0u;
      __syncthreads();
      colv[t] = v + a;
      __syncthreads();
    }
    u32 tex = colv[t] - ts;
    u32 ex0 = tex, ex1 = tex + c0, ex2 = ex1 + c1, ex3 = ex2 + c2;
    int g0 = b * BNODE + 4 * t;
    if (g0 + 0 < NN) { off[g0 + 0] = base + ex0; dinv[g0 + 0] = rsqrtf((float)(c0 + 1u)); }
    if (g0 + 1 < NN) { off[g0 + 1] = base + ex1; dinv[g0 + 1] = rsqrtf((float)(c1 + 1u)); }
    if (g0 + 2 < NN) { off[g0 + 2] = base + ex2; dinv[g0 + 2] = rsqrtf((float)(c2 + 1u)); }
    if (g0 + 3 < NN) { off[g0 + 3] = base + ex3; dinv[g0 + 3] = rsqrtf((float)(c3 + 1u)); }
    cur[4 * t] = ex0; cur[4 * t + 1] = ex1; cur[4 * t + 2] = ex2; cur[4 * t + 3] = ex3;
    __syncthreads();
    for (u32 i = t; i < cnt; i += 256) {
      u32 key = binned[base + i];
      u32 p = atomicAdd(&cur[key >> 17], 1u);
      csr[base + p] = (int)(key & 0x1FFFFu);
    }
  }
}

// ---------------- k_spec: fused spectral-norm + Wt (R9-exact) --------------
__global__ __launch_bounds__(256) void k_spec(const float* __restrict__ W,
                                              u16* __restrict__ WtG,
                                              float* __restrict__ sig) {
  __shared__ __align__(16) char MB[65536];
  __shared__ float diag[128];
  __shared__ float red[256];
  __shared__ float uvec[128];
  __shared__ float itrS;
  __shared__ int jmS;
  int t = threadIdx.x;
  int l = t & 63, w = t >> 6;
  int p = l & 15, q = l >> 4;

  for (int base = t * 4; base < NF * NH; base += 256 * 4) {
    float4 v = *(const float4*)&W[base];
    int k = base >> 7, c0 = base & 127;
#pragma unroll
    for (int i = 0; i < 4; i++) {
      int c = c0 + i;
      int inner = (k * 2) ^ ((c & 7) << 4);
      *(u16*)(MB + c * 512 + inner) = f2bf(((const float*)&v)[i]);
    }
  }
  __syncthreads();
  for (int g = t; g < 128 * 128; g += 256) {
    int c = g >> 7, k = (g & 127) * 2;
    u32 val = *(u32*)(MB + c * 512 + ((k * 2) ^ ((c & 7) << 4)));
    ((u32*)WtG)[g] = val;
  }

  f32x4 acc[2][8] = {};
#pragma unroll
  for (int ks = 0; ks < 8; ks++) {
    int kb = (ks * 32 + q * 8) * 2;
    short8 afr[2], bfr[8];
#pragma unroll
    for (int m = 0; m < 2; m++) {
      int ra = w * 32 + m * 16 + p;
      afr[m] = *(const short8*)(MB + ra * 512 + (kb ^ ((ra & 7) << 4)));
    }
#pragma unroll
    for (int n = 0; n < 8; n++) {
      int r = n * 16 + p;
      bfr[n] = *(const short8*)(MB + r * 512 + (kb ^ ((r & 7) << 4)));
    }
#pragma unroll
    for (int m = 0; m < 2; m++)
#pragma unroll
      for (int n = 0; n < 8; n++)
        acc[m][n] = __builtin_amdgcn_mfma_f32_16x16x32_bf16(afr[m], bfr[n], acc[m][n], 0, 0, 0);
  }
#pragma unroll
  for (int m = 0; m < 2; m++)
#pragma unroll
    for (int n = 0; n < 8; n++)
#pragma unroll
      for (int g = 0; g < 4; g++) {
        int r = w * 32 + m * 16 + q * 4 + g;
        int c = n * 16 + p;
        if (r == c) diag[r] = acc[m][n][g];
      }
  __syncthreads();
  if (t == 0) {
    float s = 0.f;
    for (int i = 0; i < 128; i++) s += diag[i];
    itrS = 1.0f / s;
  }
  __syncthreads();
  {
    float itr = itrS;
    char* mb0 = MB;
#pragma unroll
    for (int m = 0; m < 2; m++)
#pragma unroll
      for (int n = 0; n < 8; n++)
#pragma unroll
        for (int g = 0; g < 4; g++) {
          int r = w * 32 + m * 16 + q * 4 + g;
          int c = n * 16 + p;
          *(u16*)(mb0 + r * 256 + ((c * 2) ^ ((r & 7) << 4))) = f2bf(acc[m][n][g] * itr);
        }
  }

  char* src = MB;
  char* dst = MB + 32768;
  for (int s = 0; s < 8; s++) {
    __syncthreads();
    f32x4 mac[2][8] = {};
#pragma unroll
    for (int ks = 0; ks < 4; ks++) {
      int kb = (ks * 32 + q * 8) * 2;
      short8 afr[2], bfr[8];
#pragma unroll
      for (int m = 0; m < 2; m++) {
        int ra = w * 32 + m * 16 + p;
        afr[m] = *(const short8*)(src + ra * 256 + (kb ^ ((ra & 7) << 4)));
      }
#pragma unroll
      for (int n = 0; n < 8; n++) {
        int r = n * 16 + p;
        bfr[n] = *(const short8*)(src + r * 256 + (kb ^ ((r & 7) << 4)));
      }
#pragma unroll
      for (int m = 0; m < 2; m++)
#pragma unroll
        for (int n = 0; n < 8; n++)
          mac[m][n] = __builtin_amdgcn_mfma_f32_16x16x32_bf16(afr[m], bfr[n], mac[m][n], 0, 0, 0);
    }
#pragma unroll
    for (int m = 0; m < 2; m++)
#pragma unroll
      for (int n = 0; n < 8; n++)
#pragma unroll
        for (int g = 0; g < 4; g++) {
          int r = w * 32 + m * 16 + q * 4 + g;
          int c = n * 16 + p;
          if (r == c) diag[r] = mac[m][n][g];
        }
    __syncthreads();
    if (t == 0) {
      float ss = 0.f;
      for (int i = 0; i < 128; i++) ss += diag[i];
      itrS = 1.0f / ss;
    }
    __syncthreads();
    float it2 = itrS;
#pragma unroll
    for (int m = 0; m < 2; m++)
#pragma unroll
      for (int n = 0; n < 8; n++)
#pragma unroll
        for (int g = 0; g < 4; g++) {
          int r = w * 32 + m * 16 + q * 4 + g;
          int c = n * 16 + p;
          *(u16*)(dst + r * 256 + ((c * 2) ^ ((r & 7) << 4))) = f2bf(mac[m][n][g] * it2);
        }
    char* tmp = src; src = dst; dst = tmp;
  }
  __syncthreads();

  if (t == 0) {
    int jm = 0;
    float bm = diag[0];
    for (int i = 1; i < 128; i++)
      if (diag[i] > bm) { bm = diag[i]; jm = i; }
    jmS = jm;
  }
  __syncthreads();
  int jm = jmS;
  if (t < 128) {
    u16 hv = *(u16*)(src + jm * 256 + ((t * 2) ^ ((jm & 7) << 4)));
    uvec[t] = __uint_as_float(((u32)hv) << 16);
  }
  __syncthreads();
  {
    float a2 = 0.f;
    const float* wr = &W[t * NH];
    for (int k = 0; k < NH; k++) a2 += wr[k] * uvec[k];
    red[t] = a2 * a2;
  }
  __syncthreads();
  if (t == 0) {
    float num = 0.f;
    for (int i = 0; i < 256; i++) num += red[i];
    float den = 0.f;
    for (int i = 0; i < 128; i++) den += uvec[i] * uvec[i];
    sig[0] = rsqrtf(num / den);  // 1/sigma
  }
}

// ---------------- MFMA GEMM, barrier-free main loop (R6-exact) -------------
__global__ __launch_bounds__(256) void k_mfma(const float* __restrict__ x,
                                              const u16* __restrict__ Wt,
                                              const float* __restrict__ dinv,
                                              u16* __restrict__ hs) {
  __shared__ __align__(16) u16 tile[128 * 128];
  int t = threadIdx.x;
  int l = t & 63, w = t >> 6;
  int row0 = blockIdx.x * 128;
  int lr = l & 15;
  int lk = (l >> 4) * 8;

  long arow[2];
#pragma unroll
  for (int m = 0; m < 2; m++) {
    int r = row0 + w * 32 + m * 16 + lr;
    arow[m] = (long)((r < NN) ? r : (NN - 1)) * NF;
  }

  f32x4 acc[2][8] = {};
  short8 afr[2][2];

#define LOADA(ph, k0)                                                        \
  {                                                                          \
    _Pragma("unroll") for (int m = 0; m < 2; m++) {                          \
      float4 p0 = *(const float4*)&x[arow[m] + (k0) + lk];                   \
      float4 p1 = *(const float4*)&x[arow[m] + (k0) + lk + 4];               \
      u32 wd[4];                                                             \
      wd[0] = (u32)f2bf(p0.x) | ((u32)f2bf(p0.y) << 16);                     \
      wd[1] = (u32)f2bf(p0.z) | ((u32)f2bf(p0.w) << 16);                     \
      wd[2] = (u32)f2bf(p1.x) | ((u32)f2bf(p1.y) << 16);                     \
      wd[3] = (u32)f2bf(p1.z) | ((u32)f2bf(p1.w) << 16);                     \
      afr[ph][m] = *(short8*)wd;                                             \
    }                                                                        \
  }

  LOADA(0, 0)
#pragma unroll
  for (int ks = 0; ks < 8; ks++) {
    int cur = ks & 1, nxt = cur ^ 1;
    if (ks < 7) LOADA(nxt, (ks + 1) * 32)
    short8 bfr[8];
#pragma unroll
    for (int n = 0; n < 8; n++)
      bfr[n] = *(const short8*)&Wt[(n * 16 + lr) * NF + ks * 32 + lk];
#pragma unroll
    for (int m = 0; m < 2; m++)
#pragma unroll
      for (int n = 0; n < 8; n++)
        acc[m][n] = __builtin_amdgcn_mfma_f32_16x16x32_bf16(afr[cur][m], bfr[n], acc[m][n], 0, 0, 0);
  }
#undef LOADA

#pragma unroll
  for (int m = 0; m < 2; m++) {
    int rbl = w * 32 + m * 16 + (l >> 4) * 4;
    float dv[4];
#pragma unroll
    for (int g = 0; g < 4; g++) {
      int r = row0 + rbl + g;
      dv[g] = (r < NN) ? dinv[r] : 0.f;
    }
#pragma unroll
    for (int n = 0; n < 8; n++)
#pragma unroll
      for (int g = 0; g < 4; g++)
        tile[(rbl + g) * 128 + n * 16 + lr] = f2bf(acc[m][n][g] * dv[g]);
  }
  __syncthreads();
  const uint4* tl = (const uint4*)tile;
  size_t outb = (size_t)row0 * NH;
#pragma unroll
  for (int k = 0; k < 8; k++) {
    int u = t + k * 256;
    if (row0 + (u >> 4) < NN) *(uint4*)&hs[outb + (size_t)u * 8] = tl[u];
  }
}

// ---------------- gather + epilogue (R6-exact: wave per node) --------------
__global__ __launch_bounds__(256) void k_gather(const u16* __restrict__ hs,
                                                const int* __restrict__ csr,
                                                const u32* __restrict__ off,
                                                const float* __restrict__ dinv,
                                                const float* __restrict__ b,
                                                const float* __restrict__ pa,
                                                const float* __restrict__ sig,
                                                float* __restrict__ out) {
  int wid = threadIdx.x >> 6;
  int lane = threadIdx.x & 63;
  int n = blockIdx.x * 4 + wid;
  if (n >= NN) return;
  u32 s0 = off[n], s1 = off[n + 1];
  const u32* hrow = (const u32*)hs;
  float ax, ay;
  {
    u32 u = hrow[(size_t)n * 64 + lane];
    ax = bflo(u); ay = bfhi(u);
  }
  u32 e = s0;
  for (; e + 4 <= s1; e += 4) {
    int i0 = csr[e], i1 = csr[e + 1], i2 = csr[e + 2], i3 = csr[e + 3];
    u32 u0 = hrow[(size_t)i0 * 64 + lane];
    u32 u1 = hrow[(size_t)i1 * 64 + lane];
    u32 u2 = hrow[(size_t)i2 * 64 + lane];
    u32 u3 = hrow[(size_t)i3 * 64 + lane];
    ax += bflo(u0) + bflo(u1) + bflo(u2) + bflo(u3);
    ay += bfhi(u0) + bfhi(u1) + bfhi(u2) + bfhi(u3);
  }
  for (; e < s1; e++) {
    u32 u = hrow[(size_t)csr[e] * 64 + lane];
    ax += bflo(u); ay += bfhi(u);
  }
  float dv = dinv[n] * sig[0];
  float2 bb = *(const float2*)&b[lane * 2];
  float a = pa[0];
  float v0 = ax * dv + bb.x;
  float v1 = ay * dv + bb.y;
  float2 o;
  o.x = v0 > 0.f ? v0 : a * v0;
  o.y = v1 > 0.f ? v1 : a * v1;
  *(float2*)&out[(size_t)n * NH + lane * 2] = o;
}

// ---------------- launch ----------------
extern "C" void kernel_launch(void* const* d_in, const int* in_sizes, int n_in,
                              void* d_out, int out_size, void* d_ws, size_t ws_size,
                              hipStream_t stream) {
  const float* x = (const float*)d_in[0];
  const int* ei = (const int*)d_in[1];
  const float* W = (const float*)d_in[2];
  const float* b = (const float*)d_in[3];
  const float* pa = (const float*)d_in[4];
  float* out = (float*)d_out;
  const int* row = ei;
  const int* col = ei + EE;

  char* base = (char*)d_ws;
  size_t o = 0;
  auto alloc = [&](size_t bytes) -> void* {
    void* p = base + o;
    o += (bytes + 63) & ~(size_t)63;
    return p;
  };
  u32* hist2d = (u32*)alloc((size_t)NCHUNK * BK * 4);
  u32* gtab = (u32*)alloc((size_t)NCHUNK * BK * 4);
  u32* bbaseG = (u32*)alloc((BK + 2) * 4);
  float* sig = (float*)alloc(64);
  float* dinv = (float*)alloc((size_t)NN * 4);
  u32* off = (u32*)alloc((size_t)(NN + 4) * 4);
  u32* binned = (u32*)alloc((size_t)EE * 4);
  int* csr = (int*)alloc((size_t)EE * 4);
  u16* Wt = (u16*)alloc((size_t)NF * NH * 2);
  u16* hs = (u16*)alloc((size_t)NN * NH * 2);
  (void)ws_size; (void)in_sizes; (void)n_in; (void)out_size;

  k_spec<<<1, 256, 0, stream>>>(W, Wt, sig);

  {
    void* kargs[] = {(void*)&row, (void*)&col, (void*)&hist2d, (void*)&gtab,
                     (void*)&bbaseG, (void*)&off, (void*)&dinv,
                     (void*)&binned, (void*)&csr};
    hipLaunchCooperativeKernel((void*)k_edges, dim3(NCHUNK), dim3(256),
                               kargs, 0, stream);
  }

  k_mfma<<<(NN + 127) / 128, 256, 0, stream>>>(x, Wt, dinv, hs);
  k_gather<<<(NN + 3) / 4, 256, 0, stream>>>(hs, csr, off, dinv, b, pa, sig, out);
}

// Round 11
// 238.134 us; speedup vs baseline: 1.6890x; 1.6890x over previous
//
#include <hip/hip_runtime.h>

#define NN 100000
#define EE 1600000
#define NF 256
#define NH 128

#define BK 98        // buckets of 1024 nodes: ceil(100000/1024)
#define BNODE 1024
#define CHUNK 4096
#define NCHUNK ((EE + CHUNK - 1) / CHUNK)  // 391
#define CAP 24576    // P2 LDS staging capacity (mean 16327, std ~128)

typedef unsigned int u32;
typedef unsigned short u16;
typedef __attribute__((ext_vector_type(8))) short short8;
typedef __attribute__((ext_vector_type(4))) float f32x4;

static __device__ __forceinline__ u16 f2bf(float f) {
  u32 u = __float_as_uint(f);
  u32 r = (u + 0x7FFFu + ((u >> 16) & 1u)) >> 16;
  return (u16)r;
}
static __device__ __forceinline__ float bflo(u32 u) { return __uint_as_float(u << 16); }
static __device__ __forceinline__ float bfhi(u32 u) { return __uint_as_float(u & 0xFFFF0000u); }

// ---------------- P0: per-chunk bucket histogram (R9-exact) ----------------
__global__ __launch_bounds__(256) void k_p0(const int* __restrict__ col,
                                            u32* __restrict__ hist2d) {
  __shared__ u32 hist[BK];
  int t = threadIdx.x;
  if (t < BK) hist[t] = 0;
  __syncthreads();
  int e0 = blockIdx.x * CHUNK;
  int e1 = min(e0 + CHUNK, EE);
  for (int e = e0 + t; e < e1; e += 256) {
    u32 d = (u32)col[e];
    atomicAdd(&hist[d >> 10], 1u);
  }
  __syncthreads();
  if (t < BK) hist2d[blockIdx.x * BK + t] = hist[t];
}

// ============ k_bs_spec: block 0 = bucket scan, block 1 = spectral =========
__global__ __launch_bounds__(256) void k_bs_spec(const u32* __restrict__ hist2d,
                                                 u32* __restrict__ bcnt,
                                                 u32* __restrict__ bbase,
                                                 u32* __restrict__ gcur,
                                                 u32* __restrict__ off,
                                                 const float* __restrict__ W,
                                                 u16* __restrict__ WtG,
                                                 float* __restrict__ sig) {
  __shared__ __align__(16) char MB[65536];
  __shared__ float diag[128];
  __shared__ float red[256];
  __shared__ float uvec[128];
  __shared__ float itrS;
  __shared__ int jmS;
  int t = threadIdx.x;

  if (blockIdx.x == 0) {
    // ---------- bucket reduce + scan (R9 k_bscan body) ----------
    u32* c = (u32*)MB;
    if (t < BK) {
      u32 s = 0;
      for (int ch = 0; ch < NCHUNK; ch++) s += hist2d[ch * BK + t];
      c[t] = s;
    }
    __syncthreads();
    if (t == 0) {
      u32 s = 0;
      for (int b2 = 0; b2 < BK; b2++) {
        bcnt[b2] = c[b2];
        bbase[b2] = s;
        gcur[b2] = s;
        s += c[b2];
      }
      off[NN] = EE;
    }
    return;
  }

  // ---------- spectral norm + Wt (R9 k_spec body) ----------
  int l = t & 63, w = t >> 6;
  int p = l & 15, q = l >> 4;

  for (int base = t * 4; base < NF * NH; base += 256 * 4) {
    float4 v = *(const float4*)&W[base];
    int k = base >> 7, c0 = base & 127;
#pragma unroll
    for (int i = 0; i < 4; i++) {
      int c = c0 + i;
      int inner = (k * 2) ^ ((c & 7) << 4);
      *(u16*)(MB + c * 512 + inner) = f2bf(((const float*)&v)[i]);
    }
  }
  __syncthreads();
  for (int g = t; g < 128 * 128; g += 256) {
    int c = g >> 7, k = (g & 127) * 2;
    u32 val = *(u32*)(MB + c * 512 + ((k * 2) ^ ((c & 7) << 4)));
    ((u32*)WtG)[g] = val;
  }

  f32x4 acc[2][8] = {};
#pragma unroll
  for (int ks = 0; ks < 8; ks++) {
    int kb = (ks * 32 + q * 8) * 2;
    short8 afr[2], bfr[8];
#pragma unroll
    for (int m = 0; m < 2; m++) {
      int ra = w * 32 + m * 16 + p;
      afr[m] = *(const short8*)(MB + ra * 512 + (kb ^ ((ra & 7) << 4)));
    }
#pragma unroll
    for (int n = 0; n < 8; n++) {
      int r = n * 16 + p;
      bfr[n] = *(const short8*)(MB + r * 512 + (kb ^ ((r & 7) << 4)));
    }
#pragma unroll
    for (int m = 0; m < 2; m++)
#pragma unroll
      for (int n = 0; n < 8; n++)
        acc[m][n] = __builtin_amdgcn_mfma_f32_16x16x32_bf16(afr[m], bfr[n], acc[m][n], 0, 0, 0);
  }
#pragma unroll
  for (int m = 0; m < 2; m++)
#pragma unroll
    for (int n = 0; n < 8; n++)
#pragma unroll
      for (int g = 0; g < 4; g++) {
        int r = w * 32 + m * 16 + q * 4 + g;
        int c = n * 16 + p;
        if (r == c) diag[r] = acc[m][n][g];
      }
  __syncthreads();
  if (t == 0) {
    float s = 0.f;
    for (int i = 0; i < 128; i++) s += diag[i];
    itrS = 1.0f / s;
  }
  __syncthreads();
  {
    float itr = itrS;
    char* mb0 = MB;
#pragma unroll
    for (int m = 0; m < 2; m++)
#pragma unroll
      for (int n = 0; n < 8; n++)
#pragma unroll
        for (int g = 0; g < 4; g++) {
          int r = w * 32 + m * 16 + q * 4 + g;
          int c = n * 16 + p;
          *(u16*)(mb0 + r * 256 + ((c * 2) ^ ((r & 7) << 4))) = f2bf(acc[m][n][g] * itr);
        }
  }

  char* src = MB;
  char* dst = MB + 32768;
  for (int s = 0; s < 8; s++) {
    __syncthreads();
    f32x4 mac[2][8] = {};
#pragma unroll
    for (int ks = 0; ks < 4; ks++) {
      int kb = (ks * 32 + q * 8) * 2;
      short8 afr[2], bfr[8];
#pragma unroll
      for (int m = 0; m < 2; m++) {
        int ra = w * 32 + m * 16 + p;
        afr[m] = *(const short8*)(src + ra * 256 + (kb ^ ((ra & 7) << 4)));
      }
#pragma unroll
      for (int n = 0; n < 8; n++) {
        int r = n * 16 + p;
        bfr[n] = *(const short8*)(src + r * 256 + (kb ^ ((r & 7) << 4)));
      }
#pragma unroll
      for (int m = 0; m < 2; m++)
#pragma unroll
        for (int n = 0; n < 8; n++)
          mac[m][n] = __builtin_amdgcn_mfma_f32_16x16x32_bf16(afr[m], bfr[n], mac[m][n], 0, 0, 0);
    }
#pragma unroll
    for (int m = 0; m < 2; m++)
#pragma unroll
      for (int n = 0; n < 8; n++)
#pragma unroll
        for (int g = 0; g < 4; g++) {
          int r = w * 32 + m * 16 + q * 4 + g;
          int c = n * 16 + p;
          if (r == c) diag[r] = mac[m][n][g];
        }
    __syncthreads();
    if (t == 0) {
      float ss = 0.f;
      for (int i = 0; i < 128; i++) ss += diag[i];
      itrS = 1.0f / ss;
    }
    __syncthreads();
    float it2 = itrS;
#pragma unroll
    for (int m = 0; m < 2; m++)
#pragma unroll
      for (int n = 0; n < 8; n++)
#pragma unroll
        for (int g = 0; g < 4; g++) {
          int r = w * 32 + m * 16 + q * 4 + g;
          int c = n * 16 + p;
          *(u16*)(dst + r * 256 + ((c * 2) ^ ((r & 7) << 4))) = f2bf(mac[m][n][g] * it2);
        }
    char* tmp = src; src = dst; dst = tmp;
  }
  __syncthreads();

  if (t == 0) {
    int jm = 0;
    float bm = diag[0];
    for (int i = 1; i < 128; i++)
      if (diag[i] > bm) { bm = diag[i]; jm = i; }
    jmS = jm;
  }
  __syncthreads();
  int jm = jmS;
  if (t < 128) {
    u16 hv = *(u16*)(src + jm * 256 + ((t * 2) ^ ((jm & 7) << 4)));
    uvec[t] = __uint_as_float(((u32)hv) << 16);
  }
  __syncthreads();
  {
    float a2 = 0.f;
    const float* wr = &W[t * NH];
    for (int k = 0; k < NH; k++) a2 += wr[k] * uvec[k];
    red[t] = a2 * a2;
  }
  __syncthreads();
  if (t == 0) {
    float num = 0.f;
    for (int i = 0; i < 256; i++) num += red[i];
    float den = 0.f;
    for (int i = 0; i < 128; i++) den += uvec[i] * uvec[i];
    sig[0] = rsqrtf(num / den);  // 1/sigma
  }
}

// ---------------- P1: counting-sort edges into buckets (R9-exact) ----------
__global__ __launch_bounds__(256) void k_p1(const int* __restrict__ row,
                                            const int* __restrict__ col,
                                            u32* __restrict__ gcur,
                                            u32* __restrict__ binned) {
  __shared__ u32 keybuf[CHUNK];
  __shared__ unsigned char bktbuf[CHUNK];
  __shared__ u32 hist[BK], lstart[BK], lofs[BK], gb[BK];
  int t = threadIdx.x;
  if (t < BK) hist[t] = 0;
  __syncthreads();
  int e0 = blockIdx.x * CHUNK;
  int n = min(CHUNK, EE - e0);
  for (int i = t; i < n; i += 256) {
    u32 d = (u32)col[e0 + i];
    atomicAdd(&hist[d >> 10], 1u);
  }
  __syncthreads();
  if (t == 0) {
    u32 s = 0;
    for (int b = 0; b < BK; b++) { lstart[b] = s; lofs[b] = s; s += hist[b]; }
  }
  __syncthreads();
  if (t < BK && hist[t]) gb[t] = atomicAdd(&gcur[t], hist[t]);
  __syncthreads();
  for (int i = t; i < n; i += 256) {
    u32 d = (u32)col[e0 + i];
    u32 s = (u32)row[e0 + i];
    u32 b = d >> 10;
    u32 p = atomicAdd(&lofs[b], 1u);
    keybuf[p] = ((d & 1023u) << 17) | s;
    bktbuf[p] = (unsigned char)b;
  }
  __syncthreads();
  for (int i = t; i < n; i += 256) {
    u32 b = bktbuf[i];
    binned[gb[b] + ((u32)i - lstart[b])] = keybuf[i];
  }
}

// ---------------- P2: per-bucket counting sort in LDS (R9-exact) -----------
__global__ __launch_bounds__(1024) void k_p2(const u32* __restrict__ binned,
                                             const u32* __restrict__ bbase,
                                             const u32* __restrict__ bcnt,
                                             u32* __restrict__ off,
                                             float* __restrict__ dinv,
                                             int* __restrict__ csr) {
  __shared__ u32 hist[BNODE];
  __shared__ u32 loff[BNODE];
  __shared__ u32 cur[BNODE];
  __shared__ u32 stage[CAP];
  int b = blockIdx.x, t = threadIdx.x;
  u32 base = bbase[b], cnt = bcnt[b];
  hist[t] = 0;
  __syncthreads();
  for (u32 i = t; i < cnt; i += BNODE) {
    u32 key = binned[base + i];
    atomicAdd(&hist[key >> 17], 1u);
  }
  __syncthreads();
  u32 v = hist[t];
  loff[t] = v;
  __syncthreads();
  for (int d = 1; d < BNODE; d <<= 1) {
    u32 x = loff[t];
    u32 y = (t >= d) ? loff[t - d] : 0u;
    __syncthreads();
    loff[t] = x + y;
    __syncthreads();
  }
  u32 ex = loff[t] - v;
  cur[t] = ex;
  int g = b * BNODE + t;
  if (g < NN) {
    off[g] = base + ex;
    dinv[g] = rsqrtf((float)(v + 1u));
  }
  __syncthreads();
  if (cnt <= CAP) {
    for (u32 i = t; i < cnt; i += BNODE) {
      u32 key = binned[base + i];
      u32 p = atomicAdd(&cur[key >> 17], 1u);
      stage[p] = key & 0x1FFFFu;
    }
    __syncthreads();
    for (u32 i = t; i < cnt; i += BNODE) csr[base + i] = (int)stage[i];
  } else {
    for (u32 i = t; i < cnt; i += BNODE) {
      u32 key = binned[base + i];
      u32 p = atomicAdd(&cur[key >> 17], 1u);
      csr[base + p] = (int)(key & 0x1FFFFu);
    }
  }
}

// ---------------- MFMA GEMM, barrier-free; sliced-2 hs output --------------
// hs layout: [2][NN][64] bf16 (slice = 12.8 MB).
__global__ __launch_bounds__(256) void k_mfma(const float* __restrict__ x,
                                              const u16* __restrict__ Wt,
                                              const float* __restrict__ dinv,
                                              u16* __restrict__ hs) {
  __shared__ __align__(16) u16 tile[128 * 128];
  int t = threadIdx.x;
  int l = t & 63, w = t >> 6;
  int row0 = blockIdx.x * 128;
  int lr = l & 15;
  int lk = (l >> 4) * 8;

  long arow[2];
#pragma unroll
  for (int m = 0; m < 2; m++) {
    int r = row0 + w * 32 + m * 16 + lr;
    arow[m] = (long)((r < NN) ? r : (NN - 1)) * NF;
  }

  f32x4 acc[2][8] = {};
  short8 afr[2][2];

#define LOADA(ph, k0)                                                        \
  {                                                                          \
    _Pragma("unroll") for (int m = 0; m < 2; m++) {                          \
      float4 p0 = *(const float4*)&x[arow[m] + (k0) + lk];                   \
      float4 p1 = *(const float4*)&x[arow[m] + (k0) + lk + 4];               \
      u32 wd[4];                                                             \
      wd[0] = (u32)f2bf(p0.x) | ((u32)f2bf(p0.y) << 16);                     \
      wd[1] = (u32)f2bf(p0.z) | ((u32)f2bf(p0.w) << 16);                     \
      wd[2] = (u32)f2bf(p1.x) | ((u32)f2bf(p1.y) << 16);                     \
      wd[3] = (u32)f2bf(p1.z) | ((u32)f2bf(p1.w) << 16);                     \
      afr[ph][m] = *(short8*)wd;                                             \
    }                                                                        \
  }

  LOADA(0, 0)
#pragma unroll
  for (int ks = 0; ks < 8; ks++) {
    int cur = ks & 1, nxt = cur ^ 1;
    if (ks < 7) LOADA(nxt, (ks + 1) * 32)
    short8 bfr[8];
#pragma unroll
    for (int n = 0; n < 8; n++)
      bfr[n] = *(const short8*)&Wt[(n * 16 + lr) * NF + ks * 32 + lk];
#pragma unroll
    for (int m = 0; m < 2; m++)
#pragma unroll
      for (int n = 0; n < 8; n++)
        acc[m][n] = __builtin_amdgcn_mfma_f32_16x16x32_bf16(afr[cur][m], bfr[n], acc[m][n], 0, 0, 0);
  }
#undef LOADA

  // epilogue: scale, cvt, repack via LDS, store sliced-2 layout
#pragma unroll
  for (int m = 0; m < 2; m++) {
    int rbl = w * 32 + m * 16 + (l >> 4) * 4;
    float dv[4];
#pragma unroll
    for (int g = 0; g < 4; g++) {
      int r = row0 + rbl + g;
      dv[g] = (r < NN) ? dinv[r] : 0.f;
    }
#pragma unroll
    for (int n = 0; n < 8; n++)
#pragma unroll
      for (int g = 0; g < 4; g++)
        tile[(rbl + g) * 128 + n * 16 + lr] = f2bf(acc[m][n][g] * dv[g]);
  }
  __syncthreads();
  const uint4* tl = (const uint4*)tile;
#pragma unroll
  for (int k = 0; k < 8; k++) {
    int u = t + k * 256;          // uint4 idx: row = u>>4, c8 = u&15
    int r = u >> 4;
    int s = (u >> 3) & 1;         // cols 0-63 -> slice 0, 64-127 -> slice 1
    int g = u & 7;
    if (row0 + r < NN)
      *(uint4*)&hs[((size_t)s * NN + row0 + r) * 64 + g * 8] = tl[u];
  }
}

// -------- gather: sliced-2, wave per (node,slice), 2-edge parity -----------
// grid 50000: s = blk&1 (round-robin -> per-XCD single slice, 12.8MB L2 set),
// node n = (blk>>1)*4 + wave. Lanes: p=lane>>5 edge-parity, c=lane&31 u32-col.
__global__ __launch_bounds__(256) void k_gather(const u16* __restrict__ hs,
                                                const int* __restrict__ csr,
                                                const u32* __restrict__ off,
                                                const float* __restrict__ dinv,
                                                const float* __restrict__ b,
                                                const float* __restrict__ pa,
                                                const float* __restrict__ sig,
                                                float* __restrict__ out) {
  int s = blockIdx.x & 1;
  int nb = blockIdx.x >> 1;
  int wid = threadIdx.x >> 6;
  int lane = threadIdx.x & 63;
  int p = lane >> 5, c = lane & 31;
  int n = nb * 4 + wid;
  if (n >= NN) return;
  u32 s0 = off[n], s1 = off[n + 1];
  const u32* hrow = (const u32*)hs + (size_t)s * NN * 32;
  float ax = 0.f, ay = 0.f;
  if (p == 0) {  // self-loop term, counted once
    u32 u = hrow[(size_t)n * 32 + c];
    ax = bflo(u); ay = bfhi(u);
  }
  u32 e = s0 + (u32)p;
  for (; e + 6 < s1; e += 8) {
    int i0 = csr[e], i1 = csr[e + 2], i2 = csr[e + 4], i3 = csr[e + 6];
    u32 u0 = hrow[(size_t)i0 * 32 + c];
    u32 u1 = hrow[(size_t)i1 * 32 + c];
    u32 u2 = hrow[(size_t)i2 * 32 + c];
    u32 u3 = hrow[(size_t)i3 * 32 + c];
    ax += bflo(u0) + bflo(u1) + bflo(u2) + bflo(u3);
    ay += bfhi(u0) + bfhi(u1) + bfhi(u2) + bfhi(u3);
  }
  for (; e < s1; e += 2) {
    u32 u = hrow[(size_t)csr[e] * 32 + c];
    ax += bflo(u); ay += bfhi(u);
  }
  ax += __shfl_xor(ax, 32);
  ay += __shfl_xor(ay, 32);
  if (lane < 32) {
    float dv = dinv[n] * sig[0];
    float2 bb = *(const float2*)&b[s * 64 + c * 2];
    float a = pa[0];
    float v0 = ax * dv + bb.x;
    float v1 = ay * dv + bb.y;
    float2 o;
    o.x = v0 > 0.f ? v0 : a * v0;
    o.y = v1 > 0.f ? v1 : a * v1;
    *(float2*)&out[(size_t)n * NH + s * 64 + c * 2] = o;
  }
}

// ---------------- launch ----------------
extern "C" void kernel_launch(void* const* d_in, const int* in_sizes, int n_in,
                              void* d_out, int out_size, void* d_ws, size_t ws_size,
                              hipStream_t stream) {
  const float* x = (const float*)d_in[0];
  const int* ei = (const int*)d_in[1];
  const float* W = (const float*)d_in[2];
  const float* b = (const float*)d_in[3];
  const float* pa = (const float*)d_in[4];
  float* out = (float*)d_out;
  const int* row = ei;
  const int* col = ei + EE;

  char* base = (char*)d_ws;
  size_t o = 0;
  auto alloc = [&](size_t bytes) -> void* {
    void* p = base + o;
    o += (bytes + 63) & ~(size_t)63;
    return p;
  };
  u32* hist2d = (u32*)alloc((size_t)NCHUNK * BK * 4);
  u32* bcnt = (u32*)alloc(BK * 4);
  u32* bbase = (u32*)alloc(BK * 4);
  u32* gcur = (u32*)alloc(BK * 4);
  float* sig = (float*)alloc(64);
  float* dinv = (float*)alloc((size_t)NN * 4);
  u32* off = (u32*)alloc((size_t)(NN + 4) * 4);
  u32* binned = (u32*)alloc((size_t)EE * 4);
  int* csr = (int*)alloc((size_t)EE * 4);
  u16* Wt = (u16*)alloc((size_t)NF * NH * 2);
  u16* hs = (u16*)alloc((size_t)NN * NH * 2);
  (void)ws_size; (void)in_sizes; (void)n_in; (void)out_size;

  k_p0<<<NCHUNK, 256, 0, stream>>>(col, hist2d);
  k_bs_spec<<<2, 256, 0, stream>>>(hist2d, bcnt, bbase, gcur, off, W, Wt, sig);
  k_p1<<<NCHUNK, 256, 0, stream>>>(row, col, gcur, binned);
  k_p2<<<BK, BNODE, 0, stream>>>(binned, bbase, bcnt, off, dinv, csr);
  k_mfma<<<(NN + 127) / 128, 256, 0, stream>>>(x, Wt, dinv, hs);
  k_gather<<<50000, 256, 0, stream>>>(hs, csr, off, dinv, b, pa, sig, out);
}

// Round 12
// 202.545 us; speedup vs baseline: 1.9858x; 1.1757x over previous
//
#include <hip/hip_runtime.h>

#define NN 100000
#define EE 1600000
#define NF 256
#define NH 128

#define BK 98        // buckets of 1024 nodes: ceil(100000/1024)
#define BNODE 1024
#define CHUNK 4096
#define NCHUNK ((EE + CHUNK - 1) / CHUNK)  // 391
#define CAP 24576    // P2 LDS staging capacity (mean 16327, std ~128)

typedef unsigned int u32;
typedef unsigned short u16;
typedef __attribute__((ext_vector_type(8))) short short8;
typedef __attribute__((ext_vector_type(4))) float f32x4;

static __device__ __forceinline__ u16 f2bf(float f) {
  u32 u = __float_as_uint(f);
  u32 r = (u + 0x7FFFu + ((u >> 16) & 1u)) >> 16;
  return (u16)r;
}
static __device__ __forceinline__ float bflo(u32 u) { return __uint_as_float(u << 16); }
static __device__ __forceinline__ float bfhi(u32 u) { return __uint_as_float(u & 0xFFFF0000u); }

// ---------------- P0: per-chunk bucket histogram ----------------
__global__ __launch_bounds__(256) void k_p0(const int* __restrict__ col,
                                            u32* __restrict__ hist2d) {
  __shared__ u32 hist[BK];
  int t = threadIdx.x;
  if (t < BK) hist[t] = 0;
  __syncthreads();
  int e0 = blockIdx.x * CHUNK;
  int e1 = min(e0 + CHUNK, EE);
  for (int e = e0 + t; e < e1; e += 256) {
    u32 d = (u32)col[e];
    atomicAdd(&hist[d >> 10], 1u);
  }
  __syncthreads();
  if (t < BK) hist2d[blockIdx.x * BK + t] = hist[t];
}

// ============ k_bs_spec: block 0 = bucket scan, block 1 = spectral =========
__global__ __launch_bounds__(256) void k_bs_spec(const u32* __restrict__ hist2d,
                                                 u32* __restrict__ bcnt,
                                                 u32* __restrict__ bbase,
                                                 u32* __restrict__ gcur,
                                                 u32* __restrict__ off,
                                                 const float* __restrict__ W,
                                                 u16* __restrict__ WtG,
                                                 float* __restrict__ sig) {
  __shared__ __align__(16) char MB[65536];
  __shared__ float diag[128];
  __shared__ float red[256];
  __shared__ float uvec[128];
  __shared__ float itrS;
  __shared__ int jmS;
  int t = threadIdx.x;

  if (blockIdx.x == 0) {
    u32* c = (u32*)MB;
    if (t < BK) {
      u32 s = 0;
      for (int ch = 0; ch < NCHUNK; ch++) s += hist2d[ch * BK + t];
      c[t] = s;
    }
    __syncthreads();
    if (t == 0) {
      u32 s = 0;
      for (int b2 = 0; b2 < BK; b2++) {
        bcnt[b2] = c[b2];
        bbase[b2] = s;
        gcur[b2] = s;
        s += c[b2];
      }
      off[NN] = EE;
    }
    return;
  }

  int l = t & 63, w = t >> 6;
  int p = l & 15, q = l >> 4;

  for (int base = t * 4; base < NF * NH; base += 256 * 4) {
    float4 v = *(const float4*)&W[base];
    int k = base >> 7, c0 = base & 127;
#pragma unroll
    for (int i = 0; i < 4; i++) {
      int c = c0 + i;
      int inner = (k * 2) ^ ((c & 7) << 4);
      *(u16*)(MB + c * 512 + inner) = f2bf(((const float*)&v)[i]);
    }
  }
  __syncthreads();
  for (int g = t; g < 128 * 128; g += 256) {
    int c = g >> 7, k = (g & 127) * 2;
    u32 val = *(u32*)(MB + c * 512 + ((k * 2) ^ ((c & 7) << 4)));
    ((u32*)WtG)[g] = val;
  }

  f32x4 acc[2][8] = {};
#pragma unroll
  for (int ks = 0; ks < 8; ks++) {
    int kb = (ks * 32 + q * 8) * 2;
    short8 afr[2], bfr[8];
#pragma unroll
    for (int m = 0; m < 2; m++) {
      int ra = w * 32 + m * 16 + p;
      afr[m] = *(const short8*)(MB + ra * 512 + (kb ^ ((ra & 7) << 4)));
    }
#pragma unroll
    for (int n = 0; n < 8; n++) {
      int r = n * 16 + p;
      bfr[n] = *(const short8*)(MB + r * 512 + (kb ^ ((r & 7) << 4)));
    }
#pragma unroll
    for (int m = 0; m < 2; m++)
#pragma unroll
      for (int n = 0; n < 8; n++)
        acc[m][n] = __builtin_amdgcn_mfma_f32_16x16x32_bf16(afr[m], bfr[n], acc[m][n], 0, 0, 0);
  }
#pragma unroll
  for (int m = 0; m < 2; m++)
#pragma unroll
    for (int n = 0; n < 8; n++)
#pragma unroll
      for (int g = 0; g < 4; g++) {
        int r = w * 32 + m * 16 + q * 4 + g;
        int c = n * 16 + p;
        if (r == c) diag[r] = acc[m][n][g];
      }
  __syncthreads();
  if (t == 0) {
    float s = 0.f;
    for (int i = 0; i < 128; i++) s += diag[i];
    itrS = 1.0f / s;
  }
  __syncthreads();
  {
    float itr = itrS;
    char* mb0 = MB;
#pragma unroll
    for (int m = 0; m < 2; m++)
#pragma unroll
      for (int n = 0; n < 8; n++)
#pragma unroll
        for (int g = 0; g < 4; g++) {
          int r = w * 32 + m * 16 + q * 4 + g;
          int c = n * 16 + p;
          *(u16*)(mb0 + r * 256 + ((c * 2) ^ ((r & 7) << 4))) = f2bf(acc[m][n][g] * itr);
        }
  }

  char* src = MB;
  char* dst = MB + 32768;
  for (int s = 0; s < 8; s++) {
    __syncthreads();
    f32x4 mac[2][8] = {};
#pragma unroll
    for (int ks = 0; ks < 4; ks++) {
      int kb = (ks * 32 + q * 8) * 2;
      short8 afr[2], bfr[8];
#pragma unroll
      for (int m = 0; m < 2; m++) {
        int ra = w * 32 + m * 16 + p;
        afr[m] = *(const short8*)(src + ra * 256 + (kb ^ ((ra & 7) << 4)));
      }
#pragma unroll
      for (int n = 0; n < 8; n++) {
        int r = n * 16 + p;
        bfr[n] = *(const short8*)(src + r * 256 + (kb ^ ((r & 7) << 4)));
      }
#pragma unroll
      for (int m = 0; m < 2; m++)
#pragma unroll
        for (int n = 0; n < 8; n++)
          mac[m][n] = __builtin_amdgcn_mfma_f32_16x16x32_bf16(afr[m], bfr[n], mac[m][n], 0, 0, 0);
    }
#pragma unroll
    for (int m = 0; m < 2; m++)
#pragma unroll
      for (int n = 0; n < 8; n++)
#pragma unroll
        for (int g = 0; g < 4; g++) {
          int r = w * 32 + m * 16 + q * 4 + g;
          int c = n * 16 + p;
          if (r == c) diag[r] = mac[m][n][g];
        }
    __syncthreads();
    if (t == 0) {
      float ss = 0.f;
      for (int i = 0; i < 128; i++) ss += diag[i];
      itrS = 1.0f / ss;
    }
    __syncthreads();
    float it2 = itrS;
#pragma unroll
    for (int m = 0; m < 2; m++)
#pragma unroll
      for (int n = 0; n < 8; n++)
#pragma unroll
        for (int g = 0; g < 4; g++) {
          int r = w * 32 + m * 16 + q * 4 + g;
          int c = n * 16 + p;
          *(u16*)(dst + r * 256 + ((c * 2) ^ ((r & 7) << 4))) = f2bf(mac[m][n][g] * it2);
        }
    char* tmp = src; src = dst; dst = tmp;
  }
  __syncthreads();

  if (t == 0) {
    int jm = 0;
    float bm = diag[0];
    for (int i = 1; i < 128; i++)
      if (diag[i] > bm) { bm = diag[i]; jm = i; }
    jmS = jm;
  }
  __syncthreads();
  int jm = jmS;
  if (t < 128) {
    u16 hv = *(u16*)(src + jm * 256 + ((t * 2) ^ ((jm & 7) << 4)));
    uvec[t] = __uint_as_float(((u32)hv) << 16);
  }
  __syncthreads();
  {
    float a2 = 0.f;
    const float* wr = &W[t * NH];
    for (int k = 0; k < NH; k++) a2 += wr[k] * uvec[k];
    red[t] = a2 * a2;
  }
  __syncthreads();
  if (t == 0) {
    float num = 0.f;
    for (int i = 0; i < 256; i++) num += red[i];
    float den = 0.f;
    for (int i = 0; i < 128; i++) den += uvec[i] * uvec[i];
    sig[0] = rsqrtf(num / den);  // 1/sigma
  }
}

// ---------------- P1: counting-sort edges into buckets ----------
__global__ __launch_bounds__(256) void k_p1(const int* __restrict__ row,
                                            const int* __restrict__ col,
                                            u32* __restrict__ gcur,
                                            u32* __restrict__ binned) {
  __shared__ u32 keybuf[CHUNK];
  __shared__ unsigned char bktbuf[CHUNK];
  __shared__ u32 hist[BK], lstart[BK], lofs[BK], gb[BK];
  int t = threadIdx.x;
  if (t < BK) hist[t] = 0;
  __syncthreads();
  int e0 = blockIdx.x * CHUNK;
  int n = min(CHUNK, EE - e0);
  for (int i = t; i < n; i += 256) {
    u32 d = (u32)col[e0 + i];
    atomicAdd(&hist[d >> 10], 1u);
  }
  __syncthreads();
  if (t == 0) {
    u32 s = 0;
    for (int b = 0; b < BK; b++) { lstart[b] = s; lofs[b] = s; s += hist[b]; }
  }
  __syncthreads();
  if (t < BK && hist[t]) gb[t] = atomicAdd(&gcur[t], hist[t]);
  __syncthreads();
  for (int i = t; i < n; i += 256) {
    u32 d = (u32)col[e0 + i];
    u32 s = (u32)row[e0 + i];
    u32 b = d >> 10;
    u32 p = atomicAdd(&lofs[b], 1u);
    keybuf[p] = ((d & 1023u) << 17) | s;
    bktbuf[p] = (unsigned char)b;
  }
  __syncthreads();
  for (int i = t; i < n; i += 256) {
    u32 b = bktbuf[i];
    binned[gb[b] + ((u32)i - lstart[b])] = keybuf[i];
  }
}

// ---------------- P2: per-bucket counting sort in LDS ----------------
__global__ __launch_bounds__(1024) void k_p2(const u32* __restrict__ binned,
                                             const u32* __restrict__ bbase,
                                             const u32* __restrict__ bcnt,
                                             u32* __restrict__ off,
                                             float* __restrict__ dinv,
                                             int* __restrict__ csr) {
  __shared__ u32 hist[BNODE];
  __shared__ u32 loff[BNODE];
  __shared__ u32 cur[BNODE];
  __shared__ u32 stage[CAP];
  int b = blockIdx.x, t = threadIdx.x;
  u32 base = bbase[b], cnt = bcnt[b];
  hist[t] = 0;
  __syncthreads();
  for (u32 i = t; i < cnt; i += BNODE) {
    u32 key = binned[base + i];
    atomicAdd(&hist[key >> 17], 1u);
  }
  __syncthreads();
  u32 v = hist[t];
  loff[t] = v;
  __syncthreads();
  for (int d = 1; d < BNODE; d <<= 1) {
    u32 x = loff[t];
    u32 y = (t >= d) ? loff[t - d] : 0u;
    __syncthreads();
    loff[t] = x + y;
    __syncthreads();
  }
  u32 ex = loff[t] - v;
  cur[t] = ex;
  int g = b * BNODE + t;
  if (g < NN) {
    off[g] = base + ex;
    dinv[g] = rsqrtf((float)(v + 1u));
  }
  __syncthreads();
  if (cnt <= CAP) {
    for (u32 i = t; i < cnt; i += BNODE) {
      u32 key = binned[base + i];
      u32 p = atomicAdd(&cur[key >> 17], 1u);
      stage[p] = key & 0x1FFFFu;
    }
    __syncthreads();
    for (u32 i = t; i < cnt; i += BNODE) csr[base + i] = (int)stage[i];
  } else {
    for (u32 i = t; i < cnt; i += BNODE) {
      u32 key = binned[base + i];
      u32 p = atomicAdd(&cur[key >> 17], 1u);
      csr[base + p] = (int)(key & 0x1FFFFu);
    }
  }
}

// ---------------- MFMA GEMM, barrier-free main loop (R9-exact) -------------
__global__ __launch_bounds__(256) void k_mfma(const float* __restrict__ x,
                                              const u16* __restrict__ Wt,
                                              const float* __restrict__ dinv,
                                              u16* __restrict__ hs) {
  __shared__ __align__(16) u16 tile[128 * 128];
  int t = threadIdx.x;
  int l = t & 63, w = t >> 6;
  int row0 = blockIdx.x * 128;
  int lr = l & 15;
  int lk = (l >> 4) * 8;

  long arow[2];
#pragma unroll
  for (int m = 0; m < 2; m++) {
    int r = row0 + w * 32 + m * 16 + lr;
    arow[m] = (long)((r < NN) ? r : (NN - 1)) * NF;
  }

  f32x4 acc[2][8] = {};
  short8 afr[2][2];

#define LOADA(ph, k0)                                                        \
  {                                                                          \
    _Pragma("unroll") for (int m = 0; m < 2; m++) {                          \
      float4 p0 = *(const float4*)&x[arow[m] + (k0) + lk];                   \
      float4 p1 = *(const float4*)&x[arow[m] + (k0) + lk + 4];               \
      u32 wd[4];                                                             \
      wd[0] = (u32)f2bf(p0.x) | ((u32)f2bf(p0.y) << 16);                     \
      wd[1] = (u32)f2bf(p0.z) | ((u32)f2bf(p0.w) << 16);                     \
      wd[2] = (u32)f2bf(p1.x) | ((u32)f2bf(p1.y) << 16);                     \
      wd[3] = (u32)f2bf(p1.z) | ((u32)f2bf(p1.w) << 16);                     \
      afr[ph][m] = *(short8*)wd;                                             \
    }                                                                        \
  }

  LOADA(0, 0)
#pragma unroll
  for (int ks = 0; ks < 8; ks++) {
    int cur = ks & 1, nxt = cur ^ 1;
    if (ks < 7) LOADA(nxt, (ks + 1) * 32)
    short8 bfr[8];
#pragma unroll
    for (int n = 0; n < 8; n++)
      bfr[n] = *(const short8*)&Wt[(n * 16 + lr) * NF + ks * 32 + lk];
#pragma unroll
    for (int m = 0; m < 2; m++)
#pragma unroll
      for (int n = 0; n < 8; n++)
        acc[m][n] = __builtin_amdgcn_mfma_f32_16x16x32_bf16(afr[cur][m], bfr[n], acc[m][n], 0, 0, 0);
  }
#undef LOADA

#pragma unroll
  for (int m = 0; m < 2; m++) {
    int rbl = w * 32 + m * 16 + (l >> 4) * 4;
    float dv[4];
#pragma unroll
    for (int g = 0; g < 4; g++) {
      int r = row0 + rbl + g;
      dv[g] = (r < NN) ? dinv[r] : 0.f;
    }
#pragma unroll
    for (int n = 0; n < 8; n++)
#pragma unroll
      for (int g = 0; g < 4; g++)
        tile[(rbl + g) * 128 + n * 16 + lr] = f2bf(acc[m][n][g] * dv[g]);
  }
  __syncthreads();
  const uint4* tl = (const uint4*)tile;
  size_t outb = (size_t)row0 * NH;
#pragma unroll
  for (int k = 0; k < 8; k++) {
    int u = t + k * 256;
    if (row0 + (u >> 4) < NN) *(uint4*)&hs[outb + (size_t)u * 8] = tl[u];
  }
}

// -------- gather: R6 shape, 8-deep MLP unroll (wave per node) --------------
__global__ __launch_bounds__(256) void k_gather(const u16* __restrict__ hs,
                                                const int* __restrict__ csr,
                                                const u32* __restrict__ off,
                                                const float* __restrict__ dinv,
                                                const float* __restrict__ b,
                                                const float* __restrict__ pa,
                                                const float* __restrict__ sig,
                                                float* __restrict__ out) {
  int wid = threadIdx.x >> 6;
  int lane = threadIdx.x & 63;
  int n = blockIdx.x * 4 + wid;
  if (n >= NN) return;
  u32 s0 = off[n], s1 = off[n + 1];
  const u32* hrow = (const u32*)hs;
  float ax, ay;
  {
    u32 u = hrow[(size_t)n * 64 + lane];  // self-loop term
    ax = bflo(u); ay = bfhi(u);
  }
  u32 e = s0;
  for (; e + 8 <= s1; e += 8) {
    int i0 = csr[e],     i1 = csr[e + 1], i2 = csr[e + 2], i3 = csr[e + 3];
    int i4 = csr[e + 4], i5 = csr[e + 5], i6 = csr[e + 6], i7 = csr[e + 7];
    u32 u0 = hrow[(size_t)i0 * 64 + lane];
    u32 u1 = hrow[(size_t)i1 * 64 + lane];
    u32 u2 = hrow[(size_t)i2 * 64 + lane];
    u32 u3 = hrow[(size_t)i3 * 64 + lane];
    u32 u4 = hrow[(size_t)i4 * 64 + lane];
    u32 u5 = hrow[(size_t)i5 * 64 + lane];
    u32 u6 = hrow[(size_t)i6 * 64 + lane];
    u32 u7 = hrow[(size_t)i7 * 64 + lane];
    ax += bflo(u0) + bflo(u1) + bflo(u2) + bflo(u3)
        + bflo(u4) + bflo(u5) + bflo(u6) + bflo(u7);
    ay += bfhi(u0) + bfhi(u1) + bfhi(u2) + bfhi(u3)
        + bfhi(u4) + bfhi(u5) + bfhi(u6) + bfhi(u7);
  }
  for (; e + 4 <= s1; e += 4) {
    int i0 = csr[e], i1 = csr[e + 1], i2 = csr[e + 2], i3 = csr[e + 3];
    u32 u0 = hrow[(size_t)i0 * 64 + lane];
    u32 u1 = hrow[(size_t)i1 * 64 + lane];
    u32 u2 = hrow[(size_t)i2 * 64 + lane];
    u32 u3 = hrow[(size_t)i3 * 64 + lane];
    ax += bflo(u0) + bflo(u1) + bflo(u2) + bflo(u3);
    ay += bfhi(u0) + bfhi(u1) + bfhi(u2) + bfhi(u3);
  }
  for (; e < s1; e++) {
    u32 u = hrow[(size_t)csr[e] * 64 + lane];
    ax += bflo(u); ay += bfhi(u);
  }
  float dv = dinv[n] * sig[0];
  float2 bb = *(const float2*)&b[lane * 2];
  float a = pa[0];
  float v0 = ax * dv + bb.x;
  float v1 = ay * dv + bb.y;
  float2 o;
  o.x = v0 > 0.f ? v0 : a * v0;
  o.y = v1 > 0.f ? v1 : a * v1;
  *(float2*)&out[(size_t)n * NH + lane * 2] = o;
}

// ---------------- launch ----------------
extern "C" void kernel_launch(void* const* d_in, const int* in_sizes, int n_in,
                              void* d_out, int out_size, void* d_ws, size_t ws_size,
                              hipStream_t stream) {
  const float* x = (const float*)d_in[0];
  const int* ei = (const int*)d_in[1];
  const float* W = (const float*)d_in[2];
  const float* b = (const float*)d_in[3];
  const float* pa = (const float*)d_in[4];
  float* out = (float*)d_out;
  const int* row = ei;
  const int* col = ei + EE;

  char* base = (char*)d_ws;
  size_t o = 0;
  auto alloc = [&](size_t bytes) -> void* {
    void* p = base + o;
    o += (bytes + 63) & ~(size_t)63;
    return p;
  };
  u32* hist2d = (u32*)alloc((size_t)NCHUNK * BK * 4);
  u32* bcnt = (u32*)alloc(BK * 4);
  u32* bbase = (u32*)alloc(BK * 4);
  u32* gcur = (u32*)alloc(BK * 4);
  float* sig = (float*)alloc(64);
  float* dinv = (float*)alloc((size_t)NN * 4);
  u32* off = (u32*)alloc((size_t)(NN + 4) * 4);
  u32* binned = (u32*)alloc((size_t)EE * 4);
  int* csr = (int*)alloc((size_t)EE * 4);
  u16* Wt = (u16*)alloc((size_t)NF * NH * 2);
  u16* hs = (u16*)alloc((size_t)NN * NH * 2);
  (void)ws_size; (void)in_sizes; (void)n_in; (void)out_size;

  k_p0<<<NCHUNK, 256, 0, stream>>>(col, hist2d);
  k_bs_spec<<<2, 256, 0, stream>>>(hist2d, bcnt, bbase, gcur, off, W, Wt, sig);
  k_p1<<<NCHUNK, 256, 0, stream>>>(row, col, gcur, binned);
  k_p2<<<BK, BNODE, 0, stream>>>(binned, bbase, bcnt, off, dinv, csr);
  k_mfma<<<(NN + 127) / 128, 256, 0, stream>>>(x, Wt, dinv, hs);
  k_gather<<<(NN + 3) / 4, 256, 0, stream>>>(hs, csr, off, dinv, b, pa, sig, out);
}